// Round 9
// baseline (129.385 us; speedup 1.0000x reference)
//
#include <hip/hip_runtime.h>

#define B 16384
#define N_SPARSE 16
#define N_VARLEN 4
#define L 50
#define V 1000000
#define ROW (N_SPARSE + N_VARLEN * L)   // 216 ids per row
#define OUT_W (N_SPARSE + N_VARLEN)     // 20 floats per row
#define KLANES 8                        // lanes cooperating per (row, varlen feature)

// Model (R1-R8): bound by compulsory HBM fetch (47MB, caches wiped by the
// harness's 268MB poison fill between replays) moving through the random
// DEMAND-MISS path at ~1.4 TB/s (= 256 CU x ~32 MSHR x 64B / 900cy), vs
// ~6.3 TB/s for STREAMED reads. Fix: a warm kernel streams each XCD's pinned
// varlen table into its L2 at streaming rate; the main kernel's varlen
// gathers then L2-hit, and sparse's irreducible HBM demand misses overlap
// them (sparse blocks first) instead of sharing the demand-miss budget.
#define SPARSE_BLOCKS 1024
#define VARLEN_BLOCKS 2048
#define WARM_BLOCKS   2048

typedef int   v2i __attribute__((ext_vector_type(2)));
typedef float v4f __attribute__((ext_vector_type(4)));

// ---- warm kernel: stream varlen table f = (bid&7)&3 into XCD (bid&7)'s L2 ----
__global__ __launch_bounds__(256) void warm_kernel(
    const float* __restrict__ varlen_tables,
    float* __restrict__ ws)
{
    const int bid  = blockIdx.x;
    const int t    = threadIdx.x;
    const int xcd  = bid & 7;
    const int f    = xcd & 3;            // same mapping as main kernel
    const int slot = bid >> 3;           // [0,256): 4096-float chunk
    const float* tab = varlen_tables + (long)f * V;

    float acc = 0.0f;
    const int base = slot * 4096 + t * 4;    // coalesced: wave reads 4KB runs
    #pragma unroll
    for (int c = 0; c < 4; ++c) {
        const int g = base + c * 1024;
        if (g + 4 <= V) {
            const v4f w = *reinterpret_cast<const v4f*>(tab + g);  // cached load
            acc += w.x + w.y + w.z + w.w;
        }
    }
    ws[bid] = acc * 1e-30f;              // keep loads alive (d_ws is scratch)
}

__global__ __launch_bounds__(256) void emb_gather_pool_kernel(
    const int* __restrict__ X,
    const float* __restrict__ sparse_tables,
    const float* __restrict__ varlen_tables,
    float* __restrict__ out)
{
    const int bid = blockIdx.x;
    const int t   = threadIdx.x;

    if (bid < SPARSE_BLOCKS) {
        // ---- sparse single gathers, non-temporal (HBM demand misses;
        //      run FIRST to overlap the varlen L2-hit phase) ----
        const int rl  = t >> 4;                // row within block [0,16)
        const int j   = t & 15;                // sparse feature
        const int row = bid * 16 + rl;

        const int   id = __builtin_nontemporal_load(X + row * ROW + j);
        const float v  = __builtin_nontemporal_load(sparse_tables + (long)j * V + id);
        __builtin_nontemporal_store(v, out + row * OUT_W + j);
        return;
    }

    // ---- varlen masked-mean pooling, XCD-pinned per table (L2 warm) ----
    const int vb   = bid - SPARSE_BLOCKS;  // SPARSE_BLOCKS ≡ 0 mod 8, mapping holds
    const int xcd  = bid & 7;
    const int f    = xcd & 3;            // table f on XCDs f and f+4
    const int half = xcd >> 2;           // which half of the rows
    const int slot = vb >> 3;            // [0,256) row-chunk within (f, half)
    const int task = t >> 3;             // [0,32) row within block
    const int lane = t & (KLANES - 1);
    const int row  = half * (B / 2) + slot * 32 + task;

    const int*   ids = X + row * ROW + N_SPARSE + f * L;
    const float* tab = varlen_tables + (long)f * V;

    // Phase 1: id loads. 3x 8B vector loads cover ids 0..47 (8B-aligned);
    // tail 48+lane for lanes 0..1; others id=0 (nullified by mask -> exact).
    int id[7];
    #pragma unroll
    for (int k = 0; k < 3; ++k) {
        const v2i w = __builtin_nontemporal_load(
            reinterpret_cast<const v2i*>(ids + 2 * lane + 16 * k));
        id[2 * k]     = w.x;
        id[2 * k + 1] = w.y;
    }
    id[6] = (lane < 2) ? __builtin_nontemporal_load(ids + 48 + lane) : 0;

    // Phase 2: gathers (L2 hits after warm kernel). Slot 6 exec-predicated.
    float v[7];
    #pragma unroll
    for (int k = 0; k < 6; ++k) {
        v[k] = tab[id[k]];
    }
    v[6] = 0.0f;
    if (lane < 2) {
        v[6] = tab[id[6]];
    }

    // Phase 3: branch-free masked accumulate.
    float sum = 0.0f;
    float cnt = 0.0f;
    #pragma unroll
    for (int k = 0; k < 7; ++k) {
        const float m = (id[k] != 0) ? 1.0f : 0.0f;
        sum = fmaf(m, v[k], sum);
        cnt += m;
    }

    // Reduce across the aligned 8-lane group.
    #pragma unroll
    for (int off = 1; off < KLANES; off <<= 1) {
        sum += __shfl_xor(sum, off);
        cnt += __shfl_xor(cnt, off);
    }

    if (lane == 0) {
        __builtin_nontemporal_store(sum / (cnt + 1e-8f),
                                    out + row * OUT_W + N_SPARSE + f);
    }
}

extern "C" void kernel_launch(void* const* d_in, const int* in_sizes, int n_in,
                              void* d_out, int out_size, void* d_ws, size_t ws_size,
                              hipStream_t stream) {
    const int*   X             = (const int*)  d_in[0];
    const float* sparse_tables = (const float*)d_in[1];
    const float* varlen_tables = (const float*)d_in[2];
    float*       out           = (float*)d_out;
    float*       ws            = (float*)d_ws;

    warm_kernel<<<WARM_BLOCKS, 256, 0, stream>>>(varlen_tables, ws);

    const int grid = SPARSE_BLOCKS + VARLEN_BLOCKS;   // 3072
    emb_gather_pool_kernel<<<grid, 256, 0, stream>>>(X, sparse_tables, varlen_tables, out);
}